// Round 1
// baseline (591.540 us; speedup 1.0000x reference)
//
#include <hip/hip_runtime.h>
#include <cstdint>

constexpr int kNumLevels = 12;
constexpr int kHashSize = 1 << 17;
constexpr uint32_t kHashMask = (uint32_t)kHashSize - 1u;

typedef float f4 __attribute__((ext_vector_type(4)));

// Static per-level resolutions, matching max(1, int(round(16 * b**l))) with
// b = exp((ln256 - ln16)/11): [16,21,26,34,44,56,73,93,120,155,199,256]
__global__ __launch_bounds__(256) void hashenc_kernel(
    const float* __restrict__ x,       // [N,3]
    const float* __restrict__ tables,  // [12, 131072, 2]
    float* __restrict__ out,           // [N,12,2]
    int npts) {
  const float kRes[kNumLevels] = {16.f, 21.f, 26.f, 34.f,  44.f,  56.f,
                                  73.f, 93.f, 120.f, 155.f, 199.f, 256.f};
  int n = blockIdx.x * 256 + threadIdx.x;
  if (n >= npts) return;

  const float px = x[3 * n + 0];
  const float py = x[3 * n + 1];
  const float pz = x[3 * n + 2];

  const float2* __restrict__ tbl2 = reinterpret_cast<const float2*>(tables);

  float acc[kNumLevels][2];

#pragma unroll
  for (int l = 0; l < kNumLevels; ++l) {
    const float r = kRes[l];
    const float xs = px * r, ys = py * r, zs = pz * r;
    const float fx = floorf(xs), fy = floorf(ys), fz = floorf(zs);
    const float wx = xs - fx, wy = ys - fy, wz = zs - fz;
    const uint32_t ix = (uint32_t)(int32_t)fx;
    const uint32_t iy = (uint32_t)(int32_t)fy;
    const uint32_t iz = (uint32_t)(int32_t)fz;

    // incremental spatial hash (int32 wraparound == reference semantics)
    const uint32_t hx0 = ix * 73856093u, hx1 = hx0 + 73856093u;
    const uint32_t hy0 = iy * 19349663u, hy1 = hy0 + 19349663u;
    const uint32_t hz0 = iz * 83492791u, hz1 = hz0 + 83492791u;

    const float2* __restrict__ t = tbl2 + (size_t)l * kHashSize;

    // 8 independent gathers — compiler can keep all in flight
    const float2 f000 = t[(hx0 ^ hy0 ^ hz0) & kHashMask];
    const float2 f001 = t[(hx0 ^ hy0 ^ hz1) & kHashMask];
    const float2 f010 = t[(hx0 ^ hy1 ^ hz0) & kHashMask];
    const float2 f011 = t[(hx0 ^ hy1 ^ hz1) & kHashMask];
    const float2 f100 = t[(hx1 ^ hy0 ^ hz0) & kHashMask];
    const float2 f101 = t[(hx1 ^ hy0 ^ hz1) & kHashMask];
    const float2 f110 = t[(hx1 ^ hy1 ^ hz0) & kHashMask];
    const float2 f111 = t[(hx1 ^ hy1 ^ hz1) & kHashMask];

    const float ax0 = 1.f - wx, ax1 = wx;
    const float by0 = 1.f - wy, by1 = wy;
    const float cz0 = 1.f - wz, cz1 = wz;
    const float ab00 = ax0 * by0, ab01 = ax0 * by1;
    const float ab10 = ax1 * by0, ab11 = ax1 * by1;
    const float w000 = ab00 * cz0, w001 = ab00 * cz1;
    const float w010 = ab01 * cz0, w011 = ab01 * cz1;
    const float w100 = ab10 * cz0, w101 = ab10 * cz1;
    const float w110 = ab11 * cz0, w111 = ab11 * cz1;

    acc[l][0] = w000 * f000.x + w001 * f001.x + w010 * f010.x + w011 * f011.x +
                w100 * f100.x + w101 * f101.x + w110 * f110.x + w111 * f111.x;
    acc[l][1] = w000 * f000.y + w001 * f001.y + w010 * f010.y + w011 * f011.y +
                w100 * f100.y + w101 * f101.y + w110 * f110.y + w111 * f111.y;
  }

  // 24 contiguous f32 per point, 16B aligned -> 6 nontemporal float4 stores
  f4* o = reinterpret_cast<f4*>(out + (size_t)n * 24);
#pragma unroll
  for (int k = 0; k < 6; ++k) {
    f4 v;
    v.x = acc[2 * k + 0][0];
    v.y = acc[2 * k + 0][1];
    v.z = acc[2 * k + 1][0];
    v.w = acc[2 * k + 1][1];
    __builtin_nontemporal_store(v, o + k);
  }
}

extern "C" void kernel_launch(void* const* d_in, const int* in_sizes, int n_in,
                              void* d_out, int out_size, void* d_ws, size_t ws_size,
                              hipStream_t stream) {
  const float* x = (const float*)d_in[0];
  const float* tables = (const float*)d_in[1];
  float* out = (float*)d_out;
  const int npts = in_sizes[0] / 3;
  const int nblocks = (npts + 255) / 256;
  hipLaunchKernelGGL(hashenc_kernel, dim3(nblocks), dim3(256), 0, stream, x,
                     tables, out, npts);
}

// Round 5
// 488.253 us; speedup vs baseline: 1.2115x; 1.2115x over previous
//
#include <hip/hip_runtime.h>
#include <cstdint>

constexpr int kHashSize = 1 << 17;
constexpr uint32_t kHashMask = (uint32_t)kHashSize - 1u;

typedef float f2 __attribute__((ext_vector_type(2)));

// Static per-level resolutions: max(1, round(16 * b**l)), b = 16^(1/11)
__constant__ float kRes[12] = {16.f,  21.f,  26.f,  34.f,  44.f,  56.f,
                               73.f,  93.f,  120.f, 155.f, 199.f, 256.f};

// Level-group × XCD partitioned gather.
// Groups of 3 levels (3 MB of tables) pinned to an XCD pair via the
// round-robin blockIdx%8 -> XCD dispatch mapping, so each XCD's 4 MB L2
// holds only its group's tables -> gathers become L2 hits.
__global__ __launch_bounds__(256) void hashenc_grouped(
    const float* __restrict__ x,       // [N,3]
    const float* __restrict__ tables,  // [12, 131072, 2]
    float* __restrict__ out,           // [N,12,2]
    int npts, int bpg) {
  const int b = blockIdx.x;
  const int c = b & 7;                      // XCD slot (round-robin assumed)
  const int g = c >> 1;                     // level group 0..3 (levels 3g..3g+2)
  const int sub = ((b >> 3) << 1) | (c & 1);// block index within group
  if (sub >= bpg) return;
  const int n = sub * 256 + (int)threadIdx.x;
  if (n >= npts) return;

  // x: streamed once per group; nontemporal so it doesn't evict table lines
  const float px = __builtin_nontemporal_load(x + 3 * n + 0);
  const float py = __builtin_nontemporal_load(x + 3 * n + 1);
  const float pz = __builtin_nontemporal_load(x + 3 * n + 2);

  const f2* __restrict__ tbl2 = reinterpret_cast<const f2*>(tables);

  f2 accv[3];

#pragma unroll
  for (int k = 0; k < 3; ++k) {
    const int l = 3 * g + k;
    const float r = kRes[l];
    const float xs = px * r, ys = py * r, zs = pz * r;
    const float fx = floorf(xs), fy = floorf(ys), fz = floorf(zs);
    const float wx = xs - fx, wy = ys - fy, wz = zs - fz;
    const uint32_t ix = (uint32_t)(int32_t)fx;
    const uint32_t iy = (uint32_t)(int32_t)fy;
    const uint32_t iz = (uint32_t)(int32_t)fz;

    // incremental spatial hash (uint32 wraparound == reference int32 semantics)
    const uint32_t hx0 = ix * 73856093u, hx1 = hx0 + 73856093u;
    const uint32_t hy0 = iy * 19349663u, hy1 = hy0 + 19349663u;
    const uint32_t hz0 = iz * 83492791u, hz1 = hz0 + 83492791u;

    const f2* __restrict__ t = tbl2 + (size_t)l * kHashSize;

    const f2 f000 = t[(hx0 ^ hy0 ^ hz0) & kHashMask];
    const f2 f001 = t[(hx0 ^ hy0 ^ hz1) & kHashMask];
    const f2 f010 = t[(hx0 ^ hy1 ^ hz0) & kHashMask];
    const f2 f011 = t[(hx0 ^ hy1 ^ hz1) & kHashMask];
    const f2 f100 = t[(hx1 ^ hy0 ^ hz0) & kHashMask];
    const f2 f101 = t[(hx1 ^ hy0 ^ hz1) & kHashMask];
    const f2 f110 = t[(hx1 ^ hy1 ^ hz0) & kHashMask];
    const f2 f111 = t[(hx1 ^ hy1 ^ hz1) & kHashMask];

    const float ax0 = 1.f - wx, ax1 = wx;
    const float by0 = 1.f - wy, by1 = wy;
    const float cz0 = 1.f - wz, cz1 = wz;
    const float ab00 = ax0 * by0, ab01 = ax0 * by1;
    const float ab10 = ax1 * by0, ab11 = ax1 * by1;
    const float w000 = ab00 * cz0, w001 = ab00 * cz1;
    const float w010 = ab01 * cz0, w011 = ab01 * cz1;
    const float w100 = ab10 * cz0, w101 = ab10 * cz1;
    const float w110 = ab11 * cz0, w111 = ab11 * cz1;

    f2 a;
    a.x = w000 * f000.x + w001 * f001.x + w010 * f010.x + w011 * f011.x +
          w100 * f100.x + w101 * f101.x + w110 * f110.x + w111 * f111.x;
    a.y = w000 * f000.y + w001 * f001.y + w010 * f010.y + w011 * f011.y +
          w100 * f100.y + w101 * f101.y + w110 * f110.y + w111 * f111.y;
    accv[k] = a;
  }

  // this group's 3 levels: 24B at out + n*96 + g*24 (8B-aligned) — nontemporal
  f2* o = reinterpret_cast<f2*>(out + (size_t)n * 24 + g * 6);
  __builtin_nontemporal_store(accv[0], o + 0);
  __builtin_nontemporal_store(accv[1], o + 1);
  __builtin_nontemporal_store(accv[2], o + 2);
}

extern "C" void kernel_launch(void* const* d_in, const int* in_sizes, int n_in,
                              void* d_out, int out_size, void* d_ws, size_t ws_size,
                              hipStream_t stream) {
  const float* x = (const float*)d_in[0];
  const float* tables = (const float*)d_in[1];
  float* out = (float*)d_out;
  const int npts = in_sizes[0] / 3;
  const int bpg = (npts + 255) / 256;       // blocks per level-group
  const int nblocks = 8 * ((bpg + 1) / 2);  // 8 XCD slots x ceil(bpg/2)
  hipLaunchKernelGGL(hashenc_grouped, dim3(nblocks), dim3(256), 0, stream, x,
                     tables, out, npts, bpg);
}